// Round 11
// baseline (211.846 us; speedup 1.0000x reference)
//
#include <hip/hip_runtime.h>

// Problem constants (fixed by reference)
constexpr int B_   = 8;
constexpr int N_   = 2048;
constexpr int CIN_ = 128;
constexpr int F1_  = 256;
constexpr int F2_  = 256;
constexpr int F3_  = 64;
constexpr int M_   = B_ * N_;   // 16384 tokens

typedef unsigned short u16;
typedef unsigned long long u64;
typedef __attribute__((ext_vector_type(8)))  short short8v;   // 8 bf16 (4 VGPRs)
typedef __attribute__((ext_vector_type(16))) float f32x16;    // MFMA 32x32 acc

// bf16 round-to-nearest-even helpers
__device__ inline u16 f2bf(float x){
    union { float f; unsigned u; } c; c.f = x;
    unsigned r = (c.u + 0x7FFFu + ((c.u >> 16) & 1u)) >> 16;
    return (u16)r;
}
__device__ inline float bf2f(u16 h){
    union { unsigned u; float f; } c; c.u = ((unsigned)h) << 16;
    return c.f;
}

// ---------------------------------------------------------------------------
// Prep: 3-level bf16 split of x, W1, W2 (pre-swizzled: elem (r,k) at
// k ^ ((r&7)<<3) ushorts). Also zeroes loss accumulator and the cc rowmask.
// ---------------------------------------------------------------------------
constexpr int NX_  = M_ * CIN_;      // 2097152
constexpr int NW1_ = F1_ * CIN_;     // 32768
constexpr int NW2_ = F2_ * F1_;      // 65536

__global__ __launch_bounds__(256)
void split3_kernel(const float* __restrict__ x, const float* __restrict__ W1,
                   const float* __restrict__ W2,
                   u16* __restrict__ xh, u16* __restrict__ xm, u16* __restrict__ xl,
                   u16* __restrict__ w1h, u16* __restrict__ w1m, u16* __restrict__ w1l,
                   u16* __restrict__ w2h, u16* __restrict__ w2m, u16* __restrict__ w2l,
                   u64* __restrict__ rmask, float* __restrict__ lz)
{
    int id = blockIdx.x * 256 + threadIdx.x;
    if (id == 0) *lz = 0.f;
    if (id < M_) rmask[id] = 0ull;
    const float* src; u16 *oh, *om, *ol; int r, k, K;
    if (id < NX_)               { int t = id;               src = x;  r = t >> 7; k = t & 127; K = 128; oh = xh;  om = xm;  ol = xl;  }
    else if (id < NX_ + NW1_)   { int t = id - NX_;         src = W1; r = t >> 7; k = t & 127; K = 128; oh = w1h; om = w1m; ol = w1l; }
    else if (id < NX_ + NW1_ + NW2_) { int t = id - NX_ - NW1_; src = W2; r = t >> 8; k = t & 255; K = 256; oh = w2h; om = w2m; ol = w2l; }
    else return;
    float v = src[(size_t)r * K + k];
    u16 h = f2bf(v);            float vr = v - bf2f(h);
    u16 m = f2bf(vr);           u16 l = f2bf(vr - bf2f(m));
    size_t o = (size_t)r * K + (k ^ ((r & 7) << 3));
    oh[o] = h; om[o] = m; ol[o] = l;
}

// ---------------------------------------------------------------------------
// MLP layers 1,2 via 3-level-split MFMA (round-9 v2, unchanged/proven).
// ---------------------------------------------------------------------------
template<int KSTEPS, int WRITE_F32>   // K = KSTEPS*64
__global__ __launch_bounds__(256)
void gemm_mfma(const u16* __restrict__ Ah, const u16* __restrict__ Am, const u16* __restrict__ Al,
               const u16* __restrict__ Wh, const u16* __restrict__ Wm, const u16* __restrict__ Wl,
               const float* __restrict__ bias,
               u16* __restrict__ Hh, u16* __restrict__ Hm, u16* __restrict__ Hl,
               float* __restrict__ Hf)
{
    constexpr int K = KSTEPS * 64;
    __shared__ __align__(16) u16 SMEM[3*64*64 + 3*128*64];   // 73728 B
    u16* LA = SMEM;                  // [3][64*64]
    u16* LB = SMEM + 3*64*64;        // [3][128*64]
    const int tid = threadIdx.x;
    const int wv = tid >> 6, l = tid & 63;
    const int wc = wv;
    const int lr = l & 31, hl = l >> 5;
    const int m0 = blockIdx.y * 64, f0 = blockIdx.x * 128;

    const u16* Asrc[3] = {Ah, Am, Al};
    const u16* Bsrc[3] = {Wh, Wm, Wl};

    f32x16 acc[2] = {};
    auto frag = [&](const u16* arr, int row, int kb) -> short8v {
        int off = row * 64 + ((kb ^ ((row & 7) << 4)) >> 1);
        return *(const short8v*)&arr[off];
    };

    for (int s = 0; s < KSTEPS; ++s) {
        const int k0 = s * 64;
        __syncthreads();
#pragma unroll
        for (int lvl = 0; lvl < 3; ++lvl) {
#pragma unroll
            for (int p = 0; p < 2; ++p) {
                int g = tid + p * 256;
                int row = g >> 3, ch = (g & 7) * 8;
                *(short8v*)&LA[lvl*4096 + row*64 + ch] =
                    *(const short8v*)&Asrc[lvl][(size_t)(m0 + row) * K + k0 + ch];
            }
#pragma unroll
            for (int p = 0; p < 4; ++p) {
                int g = tid + p * 256;
                int row = g >> 3, ch = (g & 7) * 8;
                *(short8v*)&LB[lvl*8192 + row*64 + ch] =
                    *(const short8v*)&Bsrc[lvl][(size_t)(f0 + row) * K + k0 + ch];
            }
        }
        __syncthreads();
#pragma unroll
        for (int ks = 0; ks < 4; ++ks) {
            const int kb = ks * 32 + hl * 16;
            short8v aF[3][2], bF[3];
#pragma unroll
            for (int lvl = 0; lvl < 3; ++lvl) {
#pragma unroll
                for (int ri = 0; ri < 2; ++ri)
                    aF[lvl][ri] = frag(LA + lvl*4096, ri*32 + lr, kb);
                bF[lvl] = frag(LB + lvl*8192, wc*32 + lr, kb);
            }
            const int pl[6][2] = {{0,2},{2,0},{1,1},{0,1},{1,0},{0,0}};
#pragma unroll
            for (int pp = 0; pp < 6; ++pp)
#pragma unroll
                for (int ri = 0; ri < 2; ++ri)
                    acc[ri] = __builtin_amdgcn_mfma_f32_32x32x16_bf16(
                        aF[pl[pp][0]][ri], bF[pl[pp][1]], acc[ri], 0, 0, 0);
        }
    }

    __syncthreads();
    float* LDSF = (float*)SMEM;
#pragma unroll
    for (int ri = 0; ri < 2; ++ri)
#pragma unroll
        for (int r = 0; r < 16; ++r) {
            int row = ri*32 + (r & 3) + 8*(r >> 2) + 4*hl;
            LDSF[row*132 + wc*32 + lr] = acc[ri][r];
        }
    __syncthreads();
#pragma unroll
    for (int p = 0; p < 4; ++p) {
        int idx = tid + p * 256;
        int row = idx >> 4;
        int g8  = (idx & 15) * 8;
        float v[8], bz[8];
        *(float4*)&v[0]  = *(const float4*)&LDSF[row*132 + g8];
        *(float4*)&v[4]  = *(const float4*)&LDSF[row*132 + g8 + 4];
        *(float4*)&bz[0] = *(const float4*)(bias + f0 + g8);
        *(float4*)&bz[4] = *(const float4*)(bias + f0 + g8 + 4);
        const size_t mrow = m0 + row;
        short8v hh, mm8, ll;
#pragma unroll
        for (int j = 0; j < 8; ++j) {
            float vv = fmaxf(v[j] + bz[j], 0.f);
            v[j] = vv;
            u16 h = f2bf(vv);  float r1 = vv - bf2f(h);
            u16 m = f2bf(r1);  u16 lo = f2bf(r1 - bf2f(m));
            hh[j] = (short)h; mm8[j] = (short)m; ll[j] = (short)lo;
        }
        if constexpr (WRITE_F32) {
            *(float4*)&Hf[mrow * F2_ + f0 + g8]     = *(const float4*)&v[0];
            *(float4*)&Hf[mrow * F2_ + f0 + g8 + 4] = *(const float4*)&v[4];
        }
        const size_t ob = mrow * F2_ + ((size_t)(f0 + g8) ^ ((mrow & 7) << 3));
        *(short8v*)&Hh[ob] = hh;
        *(short8v*)&Hm[ob] = mm8;
        *(short8v*)&Hl[ob] = ll;
    }
}

// ---------------------------------------------------------------------------
// Layer-3 GEMM (fp32 VALU) fused with u / u_hi / u_lo / sq.
// Round-9 proven version: 64x64 tile, grid 256, 4x4 frags.
// ---------------------------------------------------------------------------
__global__ __launch_bounds__(256)
void gemm3_fused(const float* __restrict__ A, const float* __restrict__ W,
                 const float* __restrict__ bias, float* __restrict__ C,
                 u16* __restrict__ uh, u16* __restrict__ ul,
                 float* __restrict__ sqv)
{
    constexpr int K = 256;
    __shared__ __align__(16) float As[64][68];
    __shared__ __align__(16) float Ws[64][68];
    const int tid = threadIdx.x;
    const int tx = tid & 15, ty = tid >> 4;
    const int m0 = blockIdx.x * 64;

    float acc[4][4] = {};
    for (int k0 = 0; k0 < K; k0 += 64) {
        __syncthreads();
#pragma unroll
        for (int p = 0; p < 4; ++p) {
            int g = tid + p * 256;
            int r = g >> 4, c = (g & 15) << 2;
            float4 va = *(const float4*)(A + (size_t)(m0 + r) * K + k0 + c);
            As[c+0][r] = va.x; As[c+1][r] = va.y; As[c+2][r] = va.z; As[c+3][r] = va.w;
            float4 vw = *(const float4*)(W + (size_t)r * K + k0 + c);
            Ws[c+0][r] = vw.x; Ws[c+1][r] = vw.y; Ws[c+2][r] = vw.z; Ws[c+3][r] = vw.w;
        }
        __syncthreads();
#pragma unroll
        for (int k = 0; k < 64; ++k) {
            float a[4], w[4];
            *(float4*)&a[0] = *(const float4*)&As[k][ty << 2];
            *(float4*)&w[0] = *(const float4*)&Ws[k][tx << 2];
#pragma unroll
            for (int i = 0; i < 4; ++i)
#pragma unroll
                for (int j = 0; j < 4; ++j)
                    acc[i][j] = fmaf(a[i], w[j], acc[i][j]);
        }
    }

    float4 bz = *(const float4*)(bias + (tx << 2));
    const int slot = tx >> 1;
    const int hoff = (tx & 1) * 4;
#pragma unroll
    for (int i = 0; i < 4; ++i) {
        const int m = m0 + (ty << 2) + i;
        float o[4];
        o[0] = acc[i][0] + bz.x; o[1] = acc[i][1] + bz.y;
        o[2] = acc[i][2] + bz.z; o[3] = acc[i][3] + bz.w;
        *(float4*)(C + (size_t)m * F3_ + (tx << 2)) = *(const float4*)&o[0];
        ushort4 h4, l4;
        h4.x = f2bf(o[0]); l4.x = f2bf(o[0] - bf2f(h4.x));
        h4.y = f2bf(o[1]); l4.y = f2bf(o[1] - bf2f(h4.y));
        h4.z = f2bf(o[2]); l4.z = f2bf(o[2] - bf2f(h4.z));
        h4.w = f2bf(o[3]); l4.w = f2bf(o[3] - bf2f(h4.w));
        const int sb = (((slot * 16) ^ ((m & 7) << 4)) >> 1) + hoff;
        *(ushort4*)&uh[(size_t)m * 64 + sb] = h4;
        *(ushort4*)&ul[(size_t)m * 64 + sb] = l4;
        float s = o[0]*o[0] + o[1]*o[1] + o[2]*o[2] + o[3]*o[3];
#pragma unroll
        for (int msk = 1; msk <= 8; msk <<= 1) s += __shfl_xor(s, msk, 64);
        if (tx == 0) sqv[m] = s;
    }
}

// ---------------------------------------------------------------------------
// Adjacency via split-bf16 MFMA — v3: LDS-FREE. uh/ul are stored in global
// pre-swizzled in the exact fragment byte layout, so LDS staging was a pure
// pass-through copy: load fragments DIRECTLY from global (bit-identical).
// No __syncthreads, LDS=0 -> occupancy limited only by VGPRs. Full 16x16 grid
// (round-10's upper-tri + transpose bundle regressed; reverted).
// 4 waves = 2x2 quadrants of a 128x128 tile for L1 panel reuse.
// ---------------------------------------------------------------------------
__global__ __launch_bounds__(256)
void adj_mfma(const u16* __restrict__ uh, const u16* __restrict__ ul,
              const float* __restrict__ uf, const float* __restrict__ sqv,
              unsigned* __restrict__ adj, u64* __restrict__ rmask)
{
    const int tid = threadIdx.x;
    const int jt = blockIdx.x, it = blockIdx.y, b = blockIdx.z;
    const int i0 = it * 128, j0 = jt * 128;
    const size_t ub = (size_t)b * N_;

    const int w  = tid >> 6, l = tid & 63;
    const int wr = w >> 1,  wc = w & 1;
    const int lr = l & 31,  hl = l >> 5;

    const u16* uhI = uh + (ub + i0) * 64;
    const u16* ulI = ul + (ub + i0) * 64;
    const u16* uhJ = uh + (ub + j0) * 64;
    const u16* ulJ = ul + (ub + j0) * 64;

    f32x16 acc[2][2] = {};
    auto frag = [&](const u16* arr, int row, int kb) -> short8v {
        int off = row * 64 + ((kb ^ ((row & 7) << 4)) >> 1);
        return *(const short8v*)&arr[off];
    };
#pragma unroll
    for (int ks = 0; ks < 4; ++ks) {
        const int kb = ks * 32 + hl * 16;
        short8v aH[2], aL[2], bH[2], bL[2];
#pragma unroll
        for (int ri = 0; ri < 2; ++ri) {
            aH[ri] = frag(uhI, wr * 64 + ri * 32 + lr, kb);
            aL[ri] = frag(ulI, wr * 64 + ri * 32 + lr, kb);
        }
#pragma unroll
        for (int ci = 0; ci < 2; ++ci) {
            bH[ci] = frag(uhJ, wc * 64 + ci * 32 + lr, kb);
            bL[ci] = frag(ulJ, wc * 64 + ci * 32 + lr, kb);
        }
#pragma unroll
        for (int ri = 0; ri < 2; ++ri)
#pragma unroll
            for (int ci = 0; ci < 2; ++ci) {
                acc[ri][ci] = __builtin_amdgcn_mfma_f32_32x32x16_bf16(aH[ri], bH[ci], acc[ri][ci], 0, 0, 0);
                acc[ri][ci] = __builtin_amdgcn_mfma_f32_32x32x16_bf16(aH[ri], bL[ci], acc[ri][ci], 0, 0, 0);
                acc[ri][ci] = __builtin_amdgcn_mfma_f32_32x32x16_bf16(aL[ri], bH[ci], acc[ri][ci], 0, 0, 0);
            }
    }

#pragma unroll
    for (int ri = 0; ri < 2; ++ri)
#pragma unroll
    for (int ci = 0; ci < 2; ++ci) {
        const int Rb = wr * 64 + ri * 32;
        const int Cb = wc * 64 + ci * 32;
        const int jloc = Cb + lr;
        const float sj = sqv[ub + j0 + jloc];
#pragma unroll
        for (int r = 0; r < 16; ++r) {
            const int base = (r & 3) + 8 * (r >> 2);
            const int iloc = Rb + base + 4 * hl;
            const float si = sqv[ub + i0 + iloc];
            float dv = si + sj - 2.0f * acc[ri][ci][r];
            bool e;
            if (__builtin_expect(fabsf(dv - 1.0f) < 0.02f, 0)) {
                const float* ua = uf + (ub + i0 + iloc) * (size_t)F3_;
                const float* vb = uf + (ub + j0 + jloc) * (size_t)F3_;
                float dot = 0.f;
#pragma unroll 4
                for (int k = 0; k < F3_; ++k) dot = fmaf(ua[k], vb[k], dot);
                e = (si + sj - 2.0f * dot) <= 1.0f;
            } else {
                e = dv <= 1.0f;
            }
            u64 m = __ballot(e);
            if (l == 0) {
                const int I = i0 + Rb + base;
                const int W = (j0 + Cb) >> 5;
                adj[((size_t)b * 64 + W) * N_ + I]     = (unsigned)m;
                adj[((size_t)b * 64 + W) * N_ + I + 4] = (unsigned)(m >> 32);
                if ((unsigned)m)         atomicOr(&rmask[ub + I],     1ull << W);
                if ((unsigned)(m >> 32)) atomicOr(&rmask[ub + I + 4], 1ull << W);
            }
        }
    }
}

// ---------------------------------------------------------------------------
// Connected components: one block per batch, labels in LDS; hook visits only
// the adjacency words flagged in rowmask.
// ---------------------------------------------------------------------------
__global__ __launch_bounds__(1024)
void cc_kernel(const unsigned* __restrict__ adj, const u64* __restrict__ rmask,
               float* __restrict__ out)
{
    __shared__ int Lb[N_];
    __shared__ int chg;
    const int t = threadIdx.x;
    const int b = blockIdx.x;
    const unsigned* ab = adj + (size_t)b * 64 * N_;
    const u64* rm = rmask + (size_t)b * N_;

    Lb[t] = t; Lb[t + 1024] = t + 1024;
    __syncthreads();

    for (int iter = 0; iter < 24; ++iter) {
        if (t == 0) chg = 0;
        __syncthreads();
        int m[2], o[2];
#pragma unroll
        for (int h = 0; h < 2; ++h) {
            int i = t + h * 1024;
            int mm = Lb[i];
            o[h] = mm;
            const unsigned* row = ab + i;
            u64 msk = rm[i];
            while (msk) {
                int w = __ffsll(msk) - 1;
                msk &= msk - 1;
                unsigned v = row[(size_t)w * N_];
                while (v) {
                    int bit = __ffs(v) - 1;
                    v &= v - 1;
                    int lj = Lb[(w << 5) + bit];
                    mm = (lj > mm) ? lj : mm;
                }
            }
            for (int q = 0; q < N_; ++q) {
                int nx = Lb[mm];
                if (nx == mm) break;
                mm = nx;
            }
            m[h] = mm;
        }
        __syncthreads();
        Lb[t] = m[0]; Lb[t + 1024] = m[1];
        if (m[0] != o[0] || m[1] != o[1]) chg = 1;
        __syncthreads();
        if (!chg) break;
    }
    out[(size_t)b * N_ + t]        = (float)Lb[t];
    out[(size_t)b * N_ + t + 1024] = (float)Lb[t + 1024];
}

__global__ __launch_bounds__(256)
void sentinel_kernel(float* out, int n)
{
    int id = blockIdx.x * 256 + threadIdx.x;
    if (id < n) out[id] = -777.0f;
}

// ---------------------------------------------------------------------------
// Triplet loss: one block per batch; thread t handles triplet t (200 < 256).
// ---------------------------------------------------------------------------
__global__ __launch_bounds__(256)
void loss_kernel(const float* __restrict__ u, const float* __restrict__ sq,
                 const int* __restrict__ labels, const int* __restrict__ tri,
                 float* __restrict__ loss)
{
    __shared__ float ssum[256];
    __shared__ int   scnt[256];
    __shared__ int   smax[256];
    const int b = blockIdx.x, t = threadIdx.x;
    const int base = b << 11;

    float mysum = 0.f; int mycnt = 0;
    if (t < 200) {
        int a = tri[3*t+0], p = tri[3*t+1], n = tri[3*t+2];
        int la = labels[base+a], lp = labels[base+p], ln = labels[base+n];
        bool valid = (a != p) && (la == lp) && (lp != ln);
        const float4* ua = (const float4*)(u + (size_t)(base + a) * F3_);
        const float4* up = (const float4*)(u + (size_t)(base + p) * F3_);
        const float4* un = (const float4*)(u + (size_t)(base + n) * F3_);
        float dap = 0.f, dan = 0.f;
#pragma unroll
        for (int q = 0; q < 16; ++q) {
            float4 va = ua[q], vp = up[q], vn = un[q];
            dap += va.x*vp.x + va.y*vp.y + va.z*vp.z + va.w*vp.w;
            dan += va.x*vn.x + va.y*vn.y + va.z*vn.z + va.w*vn.w;
        }
        float d1 = fmaxf(sq[base+a] + sq[base+p] - 2.f*dap, 0.f);
        float d2 = fmaxf(sq[base+a] + sq[base+n] - 2.f*dan, 0.f);
        float tt = fmaxf(d1 - d2 + 2.0f, 0.f);
        if (valid) { mysum = tt; mycnt = 1; }
    }
    int mymax = 0;
    for (int idx = t; idx < N_; idx += 256) {
        int lv = labels[base + idx];
        mymax = (lv > mymax) ? lv : mymax;
    }
    ssum[t] = mysum; scnt[t] = mycnt; smax[t] = mymax;
    __syncthreads();
    for (int s = 128; s > 0; s >>= 1) {
        if (t < s) {
            ssum[t] += ssum[t + s];
            scnt[t] += scnt[t + s];
            smax[t] = (smax[t + s] > smax[t]) ? smax[t + s] : smax[t];
        }
        __syncthreads();
    }
    if (t == 0) {
        int cnt = scnt[0];
        bool use = (smax[0] > 0) && (cnt > 0);
        float contrib = use ? (ssum[0] / (float)(cnt > 1 ? cnt : 1)) : 0.f;
        atomicAdd(loss, contrib);
    }
}

// ---------------------------------------------------------------------------
extern "C" void kernel_launch(void* const* d_in, const int* in_sizes, int n_in,
                              void* d_out, int out_size, void* d_ws, size_t ws_size,
                              hipStream_t stream)
{
    const float* x      = (const float*)d_in[0];
    const int*   labels = (const int*)  d_in[1];
    const int*   tri    = (const int*)  d_in[2];
    const float* W1     = (const float*)d_in[3];
    const float* b1     = (const float*)d_in[4];
    const float* W2     = (const float*)d_in[5];
    const float* b2     = (const float*)d_in[6];
    const float* W3     = (const float*)d_in[7];
    const float* b3     = (const float*)d_in[8];
    float* out = (float*)d_out;

    char* w = (char*)d_ws;
    size_t off = 0;
    auto carve = [&](size_t bytes) -> char* {
        char* p = w + off;
        off += (bytes + 255) & ~(size_t)255;
        return p;
    };
    u16* xh  = (u16*)carve((size_t)NX_  * 2);
    u16* xm  = (u16*)carve((size_t)NX_  * 2);
    u16* xl  = (u16*)carve((size_t)NX_  * 2);
    u16* w1h = (u16*)carve((size_t)NW1_ * 2);
    u16* w1m = (u16*)carve((size_t)NW1_ * 2);
    u16* w1l = (u16*)carve((size_t)NW1_ * 2);
    u16* w2h = (u16*)carve((size_t)NW2_ * 2);
    u16* w2m = (u16*)carve((size_t)NW2_ * 2);
    u16* w2l = (u16*)carve((size_t)NW2_ * 2);
    u16* h1h = (u16*)carve((size_t)M_ * F1_ * 2);
    u16* h1m = (u16*)carve((size_t)M_ * F1_ * 2);
    u16* h1l = (u16*)carve((size_t)M_ * F1_ * 2);
    u16* h2h = (u16*)carve((size_t)M_ * F2_ * 2);
    u16* h2m = (u16*)carve((size_t)M_ * F2_ * 2);
    u16* h2l = (u16*)carve((size_t)M_ * F2_ * 2);
    float* h2f = (float*)carve((size_t)M_ * F2_ * 4);
    float* u   = (float*)carve((size_t)M_ * F3_ * 4);
    u16*   uh  = (u16*)  carve((size_t)M_ * F3_ * 2);
    u16*   ul  = (u16*)  carve((size_t)M_ * F3_ * 2);
    float* sq  = (float*)carve((size_t)M_ * 4);
    unsigned* adj = (unsigned*)carve((size_t)B_ * 64 * N_ * 4);
    u64* rmask = (u64*)carve((size_t)M_ * 8);

    if (off > ws_size) {
        hipLaunchKernelGGL(sentinel_kernel, dim3((out_size + 255) / 256), dim3(256),
                           0, stream, out, out_size);
        return;
    }

    constexpr int NTOT = NX_ + NW1_ + NW2_;
    hipLaunchKernelGGL(split3_kernel, dim3((NTOT + 255) / 256), dim3(256), 0, stream,
                       x, W1, W2, xh, xm, xl, w1h, w1m, w1l, w2h, w2m, w2l,
                       rmask, out + M_);

    hipLaunchKernelGGL((gemm_mfma<2, 0>), dim3(F1_/128, M_/64), dim3(256), 0, stream,
                       xh, xm, xl, w1h, w1m, w1l, b1, h1h, h1m, h1l, (float*)nullptr);
    hipLaunchKernelGGL((gemm_mfma<4, 1>), dim3(F2_/128, M_/64), dim3(256), 0, stream,
                       h1h, h1m, h1l, w2h, w2m, w2l, b2, h2h, h2m, h2l, h2f);

    hipLaunchKernelGGL(gemm3_fused, dim3(M_/64), dim3(256), 0, stream,
                       h2f, W3, b3, u, uh, ul, sq);

    hipLaunchKernelGGL(adj_mfma, dim3(N_/128, N_/128, B_), dim3(256), 0, stream,
                       uh, ul, u, sq, adj, rmask);

    hipLaunchKernelGGL(loss_kernel, dim3(B_), dim3(256), 0, stream,
                       u, sq, labels, tri, out + M_);

    hipLaunchKernelGGL(cc_kernel, dim3(B_), dim3(1024), 0, stream,
                       adj, rmask, out);
}

// Round 12
// 190.061 us; speedup vs baseline: 1.1146x; 1.1146x over previous
//
#include <hip/hip_runtime.h>

// Problem constants (fixed by reference)
constexpr int B_   = 8;
constexpr int N_   = 2048;
constexpr int CIN_ = 128;
constexpr int F1_  = 256;
constexpr int F2_  = 256;
constexpr int F3_  = 64;
constexpr int M_   = B_ * N_;   // 16384 tokens

typedef unsigned short u16;
typedef unsigned long long u64;
typedef __attribute__((ext_vector_type(8)))  short short8v;   // 8 bf16 (4 VGPRs)
typedef __attribute__((ext_vector_type(16))) float f32x16;    // MFMA 32x32 acc

// bf16 round-to-nearest-even helpers
__device__ inline u16 f2bf(float x){
    union { float f; unsigned u; } c; c.f = x;
    unsigned r = (c.u + 0x7FFFu + ((c.u >> 16) & 1u)) >> 16;
    return (u16)r;
}
__device__ inline float bf2f(u16 h){
    union { unsigned u; float f; } c; c.u = ((unsigned)h) << 16;
    return c.f;
}

// ---------------------------------------------------------------------------
// Prep: 3-level bf16 split of x, W1, W2 (pre-swizzled: elem (r,k) at
// k ^ ((r&7)<<3) ushorts). Also zeroes loss accumulator and the cc rowmask.
// ---------------------------------------------------------------------------
constexpr int NX_  = M_ * CIN_;      // 2097152
constexpr int NW1_ = F1_ * CIN_;     // 32768
constexpr int NW2_ = F2_ * F1_;      // 65536

__global__ __launch_bounds__(256)
void split3_kernel(const float* __restrict__ x, const float* __restrict__ W1,
                   const float* __restrict__ W2,
                   u16* __restrict__ xh, u16* __restrict__ xm, u16* __restrict__ xl,
                   u16* __restrict__ w1h, u16* __restrict__ w1m, u16* __restrict__ w1l,
                   u16* __restrict__ w2h, u16* __restrict__ w2m, u16* __restrict__ w2l,
                   u64* __restrict__ rmask, float* __restrict__ lz)
{
    int id = blockIdx.x * 256 + threadIdx.x;
    if (id == 0) *lz = 0.f;
    if (id < M_) rmask[id] = 0ull;
    const float* src; u16 *oh, *om, *ol; int r, k, K;
    if (id < NX_)               { int t = id;               src = x;  r = t >> 7; k = t & 127; K = 128; oh = xh;  om = xm;  ol = xl;  }
    else if (id < NX_ + NW1_)   { int t = id - NX_;         src = W1; r = t >> 7; k = t & 127; K = 128; oh = w1h; om = w1m; ol = w1l; }
    else if (id < NX_ + NW1_ + NW2_) { int t = id - NX_ - NW1_; src = W2; r = t >> 8; k = t & 255; K = 256; oh = w2h; om = w2m; ol = w2l; }
    else return;
    float v = src[(size_t)r * K + k];
    u16 h = f2bf(v);            float vr = v - bf2f(h);
    u16 m = f2bf(vr);           u16 l = f2bf(vr - bf2f(m));
    size_t o = (size_t)r * K + (k ^ ((r & 7) << 3));
    oh[o] = h; om[o] = m; ol[o] = l;
}

// ---------------------------------------------------------------------------
// MLP layers 1,2 via 3-level-split MFMA (round-9 v2, unchanged/proven).
// ---------------------------------------------------------------------------
template<int KSTEPS, int WRITE_F32>   // K = KSTEPS*64
__global__ __launch_bounds__(256)
void gemm_mfma(const u16* __restrict__ Ah, const u16* __restrict__ Am, const u16* __restrict__ Al,
               const u16* __restrict__ Wh, const u16* __restrict__ Wm, const u16* __restrict__ Wl,
               const float* __restrict__ bias,
               u16* __restrict__ Hh, u16* __restrict__ Hm, u16* __restrict__ Hl,
               float* __restrict__ Hf)
{
    constexpr int K = KSTEPS * 64;
    __shared__ __align__(16) u16 SMEM[3*64*64 + 3*128*64];   // 73728 B
    u16* LA = SMEM;                  // [3][64*64]
    u16* LB = SMEM + 3*64*64;        // [3][128*64]
    const int tid = threadIdx.x;
    const int wv = tid >> 6, l = tid & 63;
    const int wc = wv;
    const int lr = l & 31, hl = l >> 5;
    const int m0 = blockIdx.y * 64, f0 = blockIdx.x * 128;

    const u16* Asrc[3] = {Ah, Am, Al};
    const u16* Bsrc[3] = {Wh, Wm, Wl};

    f32x16 acc[2] = {};
    auto frag = [&](const u16* arr, int row, int kb) -> short8v {
        int off = row * 64 + ((kb ^ ((row & 7) << 4)) >> 1);
        return *(const short8v*)&arr[off];
    };

    for (int s = 0; s < KSTEPS; ++s) {
        const int k0 = s * 64;
        __syncthreads();
#pragma unroll
        for (int lvl = 0; lvl < 3; ++lvl) {
#pragma unroll
            for (int p = 0; p < 2; ++p) {
                int g = tid + p * 256;
                int row = g >> 3, ch = (g & 7) * 8;
                *(short8v*)&LA[lvl*4096 + row*64 + ch] =
                    *(const short8v*)&Asrc[lvl][(size_t)(m0 + row) * K + k0 + ch];
            }
#pragma unroll
            for (int p = 0; p < 4; ++p) {
                int g = tid + p * 256;
                int row = g >> 3, ch = (g & 7) * 8;
                *(short8v*)&LB[lvl*8192 + row*64 + ch] =
                    *(const short8v*)&Bsrc[lvl][(size_t)(f0 + row) * K + k0 + ch];
            }
        }
        __syncthreads();
#pragma unroll
        for (int ks = 0; ks < 4; ++ks) {
            const int kb = ks * 32 + hl * 16;
            short8v aF[3][2], bF[3];
#pragma unroll
            for (int lvl = 0; lvl < 3; ++lvl) {
#pragma unroll
                for (int ri = 0; ri < 2; ++ri)
                    aF[lvl][ri] = frag(LA + lvl*4096, ri*32 + lr, kb);
                bF[lvl] = frag(LB + lvl*8192, wc*32 + lr, kb);
            }
            const int pl[6][2] = {{0,2},{2,0},{1,1},{0,1},{1,0},{0,0}};
#pragma unroll
            for (int pp = 0; pp < 6; ++pp)
#pragma unroll
                for (int ri = 0; ri < 2; ++ri)
                    acc[ri] = __builtin_amdgcn_mfma_f32_32x32x16_bf16(
                        aF[pl[pp][0]][ri], bF[pl[pp][1]], acc[ri], 0, 0, 0);
        }
    }

    __syncthreads();
    float* LDSF = (float*)SMEM;
#pragma unroll
    for (int ri = 0; ri < 2; ++ri)
#pragma unroll
        for (int r = 0; r < 16; ++r) {
            int row = ri*32 + (r & 3) + 8*(r >> 2) + 4*hl;
            LDSF[row*132 + wc*32 + lr] = acc[ri][r];
        }
    __syncthreads();
#pragma unroll
    for (int p = 0; p < 4; ++p) {
        int idx = tid + p * 256;
        int row = idx >> 4;
        int g8  = (idx & 15) * 8;
        float v[8], bz[8];
        *(float4*)&v[0]  = *(const float4*)&LDSF[row*132 + g8];
        *(float4*)&v[4]  = *(const float4*)&LDSF[row*132 + g8 + 4];
        *(float4*)&bz[0] = *(const float4*)(bias + f0 + g8);
        *(float4*)&bz[4] = *(const float4*)(bias + f0 + g8 + 4);
        const size_t mrow = m0 + row;
        short8v hh, mm8, ll;
#pragma unroll
        for (int j = 0; j < 8; ++j) {
            float vv = fmaxf(v[j] + bz[j], 0.f);
            v[j] = vv;
            u16 h = f2bf(vv);  float r1 = vv - bf2f(h);
            u16 m = f2bf(r1);  u16 lo = f2bf(r1 - bf2f(m));
            hh[j] = (short)h; mm8[j] = (short)m; ll[j] = (short)lo;
        }
        if constexpr (WRITE_F32) {
            *(float4*)&Hf[mrow * F2_ + f0 + g8]     = *(const float4*)&v[0];
            *(float4*)&Hf[mrow * F2_ + f0 + g8 + 4] = *(const float4*)&v[4];
        }
        const size_t ob = mrow * F2_ + ((size_t)(f0 + g8) ^ ((mrow & 7) << 3));
        *(short8v*)&Hh[ob] = hh;
        *(short8v*)&Hm[ob] = mm8;
        *(short8v*)&Hl[ob] = ll;
    }
}

// ---------------------------------------------------------------------------
// Layer-3 GEMM (fp32 VALU) fused with u / u_hi / u_lo / sq (round-9 proven).
// ---------------------------------------------------------------------------
__global__ __launch_bounds__(256)
void gemm3_fused(const float* __restrict__ A, const float* __restrict__ W,
                 const float* __restrict__ bias, float* __restrict__ C,
                 u16* __restrict__ uh, u16* __restrict__ ul,
                 float* __restrict__ sqv)
{
    constexpr int K = 256;
    __shared__ __align__(16) float As[64][68];
    __shared__ __align__(16) float Ws[64][68];
    const int tid = threadIdx.x;
    const int tx = tid & 15, ty = tid >> 4;
    const int m0 = blockIdx.x * 64;

    float acc[4][4] = {};
    for (int k0 = 0; k0 < K; k0 += 64) {
        __syncthreads();
#pragma unroll
        for (int p = 0; p < 4; ++p) {
            int g = tid + p * 256;
            int r = g >> 4, c = (g & 15) << 2;
            float4 va = *(const float4*)(A + (size_t)(m0 + r) * K + k0 + c);
            As[c+0][r] = va.x; As[c+1][r] = va.y; As[c+2][r] = va.z; As[c+3][r] = va.w;
            float4 vw = *(const float4*)(W + (size_t)r * K + k0 + c);
            Ws[c+0][r] = vw.x; Ws[c+1][r] = vw.y; Ws[c+2][r] = vw.z; Ws[c+3][r] = vw.w;
        }
        __syncthreads();
#pragma unroll
        for (int k = 0; k < 64; ++k) {
            float a[4], w[4];
            *(float4*)&a[0] = *(const float4*)&As[k][ty << 2];
            *(float4*)&w[0] = *(const float4*)&Ws[k][tx << 2];
#pragma unroll
            for (int i = 0; i < 4; ++i)
#pragma unroll
                for (int j = 0; j < 4; ++j)
                    acc[i][j] = fmaf(a[i], w[j], acc[i][j]);
        }
    }

    float4 bz = *(const float4*)(bias + (tx << 2));
    const int slot = tx >> 1;
    const int hoff = (tx & 1) * 4;
#pragma unroll
    for (int i = 0; i < 4; ++i) {
        const int m = m0 + (ty << 2) + i;
        float o[4];
        o[0] = acc[i][0] + bz.x; o[1] = acc[i][1] + bz.y;
        o[2] = acc[i][2] + bz.z; o[3] = acc[i][3] + bz.w;
        *(float4*)(C + (size_t)m * F3_ + (tx << 2)) = *(const float4*)&o[0];
        ushort4 h4, l4;
        h4.x = f2bf(o[0]); l4.x = f2bf(o[0] - bf2f(h4.x));
        h4.y = f2bf(o[1]); l4.y = f2bf(o[1] - bf2f(h4.y));
        h4.z = f2bf(o[2]); l4.z = f2bf(o[2] - bf2f(h4.z));
        h4.w = f2bf(o[3]); l4.w = f2bf(o[3] - bf2f(h4.w));
        const int sb = (((slot * 16) ^ ((m & 7) << 4)) >> 1) + hoff;
        *(ushort4*)&uh[(size_t)m * 64 + sb] = h4;
        *(ushort4*)&ul[(size_t)m * 64 + sb] = l4;
        float s = o[0]*o[0] + o[1]*o[1] + o[2]*o[2] + o[3]*o[3];
#pragma unroll
        for (int msk = 1; msk <= 8; msk <<= 1) s += __shfl_xor(s, msk, 64);
        if (tx == 0) sqv[m] = s;
    }
}

// ---------------------------------------------------------------------------
// Adjacency via split-bf16 MFMA — v4 HYBRID:
//   hi panels staged in LDS (32 KB, half of r9 -> higher occupancy, cheap
//   batched staging);
//   lo fragments loaded DIRECTLY into registers, ISSUED AT KERNEL ENTRY so
//   their global latency hides under the staging + barrier phase (r11 showed
//   per-ks global frag loads on the MFMA chain = 6% MfmaUtil; r9 showed
//   full-LDS staging = 64 KB occupancy cap). Bytes identical either way.
// ---------------------------------------------------------------------------
__global__ __launch_bounds__(256)
void adj_mfma(const u16* __restrict__ uh, const u16* __restrict__ ul,
              const float* __restrict__ uf, const float* __restrict__ sqv,
              unsigned* __restrict__ adj, u64* __restrict__ rmask)
{
    __shared__ u16 UiH[128*64];
    __shared__ u16 UjH[128*64];
    __shared__ float sqi[128], sqj[128];
    const int tid = threadIdx.x;
    const int jt = blockIdx.x, it = blockIdx.y, b = blockIdx.z;
    const int i0 = it * 128, j0 = jt * 128;
    const size_t ub = (size_t)b * N_;

    const int w  = tid >> 6, l = tid & 63;
    const int wr = w >> 1,  wc = w & 1;
    const int lr = l & 31,  hl = l >> 5;

    const u16* ulI = ul + (ub + i0) * 64;
    const u16* ulJ = ul + (ub + j0) * 64;

    auto frag = [&](const u16* arr, int row, int kb) -> short8v {
        int off = row * 64 + ((kb ^ ((row & 7) << 4)) >> 1);
        return *(const short8v*)&arr[off];
    };

    // (1) issue ALL lo-fragment loads first — latency overlaps staging+barrier
    short8v aL[4][2], bL[4][2];
#pragma unroll
    for (int ks = 0; ks < 4; ++ks) {
        const int kb = ks * 32 + hl * 16;
#pragma unroll
        for (int ri = 0; ri < 2; ++ri)
            aL[ks][ri] = frag(ulI, wr * 64 + ri * 32 + lr, kb);
#pragma unroll
        for (int ci = 0; ci < 2; ++ci)
            bL[ks][ci] = frag(ulJ, wc * 64 + ci * 32 + lr, kb);
    }

    // (2) stage hi panels + sq into LDS
    if (tid < 128) sqi[tid] = sqv[ub + i0 + tid];
    else           sqj[tid - 128] = sqv[ub + j0 + (tid - 128)];
#pragma unroll
    for (int p = 0; p < 4; ++p) {
        int g = tid + p * 256;
        *(short8v*)&UiH[g * 8] = *(const short8v*)&uh[(ub + i0) * 64 + g * 8];
        *(short8v*)&UjH[g * 8] = *(const short8v*)&uh[(ub + j0) * 64 + g * 8];
    }
    __syncthreads();

    // (3) MFMA chains: hi frags from LDS, lo frags from registers
    f32x16 acc[2][2] = {};
#pragma unroll
    for (int ks = 0; ks < 4; ++ks) {
        const int kb = ks * 32 + hl * 16;
        short8v aH[2], bH[2];
#pragma unroll
        for (int ri = 0; ri < 2; ++ri)
            aH[ri] = frag(UiH, wr * 64 + ri * 32 + lr, kb);
#pragma unroll
        for (int ci = 0; ci < 2; ++ci)
            bH[ci] = frag(UjH, wc * 64 + ci * 32 + lr, kb);
#pragma unroll
        for (int ri = 0; ri < 2; ++ri)
#pragma unroll
            for (int ci = 0; ci < 2; ++ci) {
                acc[ri][ci] = __builtin_amdgcn_mfma_f32_32x32x16_bf16(aH[ri], bH[ci], acc[ri][ci], 0, 0, 0);
                acc[ri][ci] = __builtin_amdgcn_mfma_f32_32x32x16_bf16(aH[ri], bL[ks][ci], acc[ri][ci], 0, 0, 0);
                acc[ri][ci] = __builtin_amdgcn_mfma_f32_32x32x16_bf16(aL[ks][ri], bH[ci], acc[ri][ci], 0, 0, 0);
            }
    }

#pragma unroll
    for (int ri = 0; ri < 2; ++ri)
#pragma unroll
    for (int ci = 0; ci < 2; ++ci) {
        const int Rb = wr * 64 + ri * 32;
        const int Cb = wc * 64 + ci * 32;
        const int jloc = Cb + lr;
        const float sj = sqj[jloc];
#pragma unroll
        for (int r = 0; r < 16; ++r) {
            const int base = (r & 3) + 8 * (r >> 2);
            const int iloc = Rb + base + 4 * hl;
            const float si = sqi[iloc];
            float dv = si + sj - 2.0f * acc[ri][ci][r];
            bool e;
            if (__builtin_expect(fabsf(dv - 1.0f) < 0.02f, 0)) {
                const float* ua = uf + (ub + i0 + iloc) * (size_t)F3_;
                const float* vb = uf + (ub + j0 + jloc) * (size_t)F3_;
                float dot = 0.f;
#pragma unroll 4
                for (int k = 0; k < F3_; ++k) dot = fmaf(ua[k], vb[k], dot);
                e = (si + sj - 2.0f * dot) <= 1.0f;
            } else {
                e = dv <= 1.0f;
            }
            u64 m = __ballot(e);
            if (l == 0) {
                const int I = i0 + Rb + base;
                const int W = (j0 + Cb) >> 5;
                adj[((size_t)b * 64 + W) * N_ + I]     = (unsigned)m;
                adj[((size_t)b * 64 + W) * N_ + I + 4] = (unsigned)(m >> 32);
                if ((unsigned)m)         atomicOr(&rmask[ub + I],     1ull << W);
                if ((unsigned)(m >> 32)) atomicOr(&rmask[ub + I + 4], 1ull << W);
            }
        }
    }
}

// ---------------------------------------------------------------------------
// Connected components: one block per batch, labels in LDS; hook visits only
// the adjacency words flagged in rowmask.
// ---------------------------------------------------------------------------
__global__ __launch_bounds__(1024)
void cc_kernel(const unsigned* __restrict__ adj, const u64* __restrict__ rmask,
               float* __restrict__ out)
{
    __shared__ int Lb[N_];
    __shared__ int chg;
    const int t = threadIdx.x;
    const int b = blockIdx.x;
    const unsigned* ab = adj + (size_t)b * 64 * N_;
    const u64* rm = rmask + (size_t)b * N_;

    Lb[t] = t; Lb[t + 1024] = t + 1024;
    __syncthreads();

    for (int iter = 0; iter < 24; ++iter) {
        if (t == 0) chg = 0;
        __syncthreads();
        int m[2], o[2];
#pragma unroll
        for (int h = 0; h < 2; ++h) {
            int i = t + h * 1024;
            int mm = Lb[i];
            o[h] = mm;
            const unsigned* row = ab + i;
            u64 msk = rm[i];
            while (msk) {
                int w = __ffsll(msk) - 1;
                msk &= msk - 1;
                unsigned v = row[(size_t)w * N_];
                while (v) {
                    int bit = __ffs(v) - 1;
                    v &= v - 1;
                    int lj = Lb[(w << 5) + bit];
                    mm = (lj > mm) ? lj : mm;
                }
            }
            for (int q = 0; q < N_; ++q) {
                int nx = Lb[mm];
                if (nx == mm) break;
                mm = nx;
            }
            m[h] = mm;
        }
        __syncthreads();
        Lb[t] = m[0]; Lb[t + 1024] = m[1];
        if (m[0] != o[0] || m[1] != o[1]) chg = 1;
        __syncthreads();
        if (!chg) break;
    }
    out[(size_t)b * N_ + t]        = (float)Lb[t];
    out[(size_t)b * N_ + t + 1024] = (float)Lb[t + 1024];
}

__global__ __launch_bounds__(256)
void sentinel_kernel(float* out, int n)
{
    int id = blockIdx.x * 256 + threadIdx.x;
    if (id < n) out[id] = -777.0f;
}

// ---------------------------------------------------------------------------
// Triplet loss: one block per batch; thread t handles triplet t (200 < 256).
// ---------------------------------------------------------------------------
__global__ __launch_bounds__(256)
void loss_kernel(const float* __restrict__ u, const float* __restrict__ sq,
                 const int* __restrict__ labels, const int* __restrict__ tri,
                 float* __restrict__ loss)
{
    __shared__ float ssum[256];
    __shared__ int   scnt[256];
    __shared__ int   smax[256];
    const int b = blockIdx.x, t = threadIdx.x;
    const int base = b << 11;

    float mysum = 0.f; int mycnt = 0;
    if (t < 200) {
        int a = tri[3*t+0], p = tri[3*t+1], n = tri[3*t+2];
        int la = labels[base+a], lp = labels[base+p], ln = labels[base+n];
        bool valid = (a != p) && (la == lp) && (lp != ln);
        const float4* ua = (const float4*)(u + (size_t)(base + a) * F3_);
        const float4* up = (const float4*)(u + (size_t)(base + p) * F3_);
        const float4* un = (const float4*)(u + (size_t)(base + n) * F3_);
        float dap = 0.f, dan = 0.f;
#pragma unroll
        for (int q = 0; q < 16; ++q) {
            float4 va = ua[q], vp = up[q], vn = un[q];
            dap += va.x*vp.x + va.y*vp.y + va.z*vp.z + va.w*vp.w;
            dan += va.x*vn.x + va.y*vn.y + va.z*vn.z + va.w*vn.w;
        }
        float d1 = fmaxf(sq[base+a] + sq[base+p] - 2.f*dap, 0.f);
        float d2 = fmaxf(sq[base+a] + sq[base+n] - 2.f*dan, 0.f);
        float tt = fmaxf(d1 - d2 + 2.0f, 0.f);
        if (valid) { mysum = tt; mycnt = 1; }
    }
    int mymax = 0;
    for (int idx = t; idx < N_; idx += 256) {
        int lv = labels[base + idx];
        mymax = (lv > mymax) ? lv : mymax;
    }
    ssum[t] = mysum; scnt[t] = mycnt; smax[t] = mymax;
    __syncthreads();
    for (int s = 128; s > 0; s >>= 1) {
        if (t < s) {
            ssum[t] += ssum[t + s];
            scnt[t] += scnt[t + s];
            smax[t] = (smax[t + s] > smax[t]) ? smax[t + s] : smax[t];
        }
        __syncthreads();
    }
    if (t == 0) {
        int cnt = scnt[0];
        bool use = (smax[0] > 0) && (cnt > 0);
        float contrib = use ? (ssum[0] / (float)(cnt > 1 ? cnt : 1)) : 0.f;
        atomicAdd(loss, contrib);
    }
}

// ---------------------------------------------------------------------------
extern "C" void kernel_launch(void* const* d_in, const int* in_sizes, int n_in,
                              void* d_out, int out_size, void* d_ws, size_t ws_size,
                              hipStream_t stream)
{
    const float* x      = (const float*)d_in[0];
    const int*   labels = (const int*)  d_in[1];
    const int*   tri    = (const int*)  d_in[2];
    const float* W1     = (const float*)d_in[3];
    const float* b1     = (const float*)d_in[4];
    const float* W2     = (const float*)d_in[5];
    const float* b2     = (const float*)d_in[6];
    const float* W3     = (const float*)d_in[7];
    const float* b3     = (const float*)d_in[8];
    float* out = (float*)d_out;

    char* w = (char*)d_ws;
    size_t off = 0;
    auto carve = [&](size_t bytes) -> char* {
        char* p = w + off;
        off += (bytes + 255) & ~(size_t)255;
        return p;
    };
    u16* xh  = (u16*)carve((size_t)NX_  * 2);
    u16* xm  = (u16*)carve((size_t)NX_  * 2);
    u16* xl  = (u16*)carve((size_t)NX_  * 2);
    u16* w1h = (u16*)carve((size_t)NW1_ * 2);
    u16* w1m = (u16*)carve((size_t)NW1_ * 2);
    u16* w1l = (u16*)carve((size_t)NW1_ * 2);
    u16* w2h = (u16*)carve((size_t)NW2_ * 2);
    u16* w2m = (u16*)carve((size_t)NW2_ * 2);
    u16* w2l = (u16*)carve((size_t)NW2_ * 2);
    u16* h1h = (u16*)carve((size_t)M_ * F1_ * 2);
    u16* h1m = (u16*)carve((size_t)M_ * F1_ * 2);
    u16* h1l = (u16*)carve((size_t)M_ * F1_ * 2);
    u16* h2h = (u16*)carve((size_t)M_ * F2_ * 2);
    u16* h2m = (u16*)carve((size_t)M_ * F2_ * 2);
    u16* h2l = (u16*)carve((size_t)M_ * F2_ * 2);
    float* h2f = (float*)carve((size_t)M_ * F2_ * 4);
    float* u   = (float*)carve((size_t)M_ * F3_ * 4);
    u16*   uh  = (u16*)  carve((size_t)M_ * F3_ * 2);
    u16*   ul  = (u16*)  carve((size_t)M_ * F3_ * 2);
    float* sq  = (float*)carve((size_t)M_ * 4);
    unsigned* adj = (unsigned*)carve((size_t)B_ * 64 * N_ * 4);
    u64* rmask = (u64*)carve((size_t)M_ * 8);

    if (off > ws_size) {
        hipLaunchKernelGGL(sentinel_kernel, dim3((out_size + 255) / 256), dim3(256),
                           0, stream, out, out_size);
        return;
    }

    constexpr int NTOT = NX_ + NW1_ + NW2_;
    hipLaunchKernelGGL(split3_kernel, dim3((NTOT + 255) / 256), dim3(256), 0, stream,
                       x, W1, W2, xh, xm, xl, w1h, w1m, w1l, w2h, w2m, w2l,
                       rmask, out + M_);

    hipLaunchKernelGGL((gemm_mfma<2, 0>), dim3(F1_/128, M_/64), dim3(256), 0, stream,
                       xh, xm, xl, w1h, w1m, w1l, b1, h1h, h1m, h1l, (float*)nullptr);
    hipLaunchKernelGGL((gemm_mfma<4, 1>), dim3(F2_/128, M_/64), dim3(256), 0, stream,
                       h1h, h1m, h1l, w2h, w2m, w2l, b2, h2h, h2m, h2l, h2f);

    hipLaunchKernelGGL(gemm3_fused, dim3(M_/64), dim3(256), 0, stream,
                       h2f, W3, b3, u, uh, ul, sq);

    hipLaunchKernelGGL(adj_mfma, dim3(N_/128, N_/128, B_), dim3(256), 0, stream,
                       uh, ul, u, sq, adj, rmask);

    hipLaunchKernelGGL(loss_kernel, dim3(B_), dim3(256), 0, stream,
                       u, sq, labels, tri, out + M_);

    hipLaunchKernelGGL(cc_kernel, dim3(B_), dim3(1024), 0, stream,
                       adj, rmask, out);
}

// Round 13
// 176.177 us; speedup vs baseline: 1.2025x; 1.0788x over previous
//
#include <hip/hip_runtime.h>

// Problem constants (fixed by reference)
constexpr int B_   = 8;
constexpr int N_   = 2048;
constexpr int CIN_ = 128;
constexpr int F1_  = 256;
constexpr int F2_  = 256;
constexpr int F3_  = 64;
constexpr int M_   = B_ * N_;   // 16384 tokens

typedef unsigned short u16;
typedef unsigned long long u64;
typedef __attribute__((ext_vector_type(8)))  short short8v;   // 8 bf16 (4 VGPRs)
typedef __attribute__((ext_vector_type(16))) float f32x16;    // MFMA 32x32 acc

// bf16 round-to-nearest-even helpers
__device__ inline u16 f2bf(float x){
    union { float f; unsigned u; } c; c.f = x;
    unsigned r = (c.u + 0x7FFFu + ((c.u >> 16) & 1u)) >> 16;
    return (u16)r;
}
__device__ inline float bf2f(u16 h){
    union { unsigned u; float f; } c; c.u = ((unsigned)h) << 16;
    return c.f;
}

// ---------------------------------------------------------------------------
// Prep: 3-level bf16 split of x, W1, W2 (pre-swizzled: elem (r,k) at
// k ^ ((r&7)<<3) ushorts). Also zeroes loss accumulator and the cc rowmask.
// ---------------------------------------------------------------------------
constexpr int NX_  = M_ * CIN_;      // 2097152
constexpr int NW1_ = F1_ * CIN_;     // 32768
constexpr int NW2_ = F2_ * F1_;      // 65536

__global__ __launch_bounds__(256)
void split3_kernel(const float* __restrict__ x, const float* __restrict__ W1,
                   const float* __restrict__ W2,
                   u16* __restrict__ xh, u16* __restrict__ xm, u16* __restrict__ xl,
                   u16* __restrict__ w1h, u16* __restrict__ w1m, u16* __restrict__ w1l,
                   u16* __restrict__ w2h, u16* __restrict__ w2m, u16* __restrict__ w2l,
                   u64* __restrict__ rmask, float* __restrict__ lz)
{
    int id = blockIdx.x * 256 + threadIdx.x;
    if (id == 0) *lz = 0.f;
    if (id < M_) rmask[id] = 0ull;
    const float* src; u16 *oh, *om, *ol; int r, k, K;
    if (id < NX_)               { int t = id;               src = x;  r = t >> 7; k = t & 127; K = 128; oh = xh;  om = xm;  ol = xl;  }
    else if (id < NX_ + NW1_)   { int t = id - NX_;         src = W1; r = t >> 7; k = t & 127; K = 128; oh = w1h; om = w1m; ol = w1l; }
    else if (id < NX_ + NW1_ + NW2_) { int t = id - NX_ - NW1_; src = W2; r = t >> 8; k = t & 255; K = 256; oh = w2h; om = w2m; ol = w2l; }
    else return;
    float v = src[(size_t)r * K + k];
    u16 h = f2bf(v);            float vr = v - bf2f(h);
    u16 m = f2bf(vr);           u16 l = f2bf(vr - bf2f(m));
    size_t o = (size_t)r * K + (k ^ ((r & 7) << 3));
    oh[o] = h; om[o] = m; ol[o] = l;
}

// ---------------------------------------------------------------------------
// MLP layers 1,2 via 3-level-split MFMA (round-9 v2, unchanged/proven).
// ---------------------------------------------------------------------------
template<int KSTEPS, int WRITE_F32>   // K = KSTEPS*64
__global__ __launch_bounds__(256)
void gemm_mfma(const u16* __restrict__ Ah, const u16* __restrict__ Am, const u16* __restrict__ Al,
               const u16* __restrict__ Wh, const u16* __restrict__ Wm, const u16* __restrict__ Wl,
               const float* __restrict__ bias,
               u16* __restrict__ Hh, u16* __restrict__ Hm, u16* __restrict__ Hl,
               float* __restrict__ Hf)
{
    constexpr int K = KSTEPS * 64;
    __shared__ __align__(16) u16 SMEM[3*64*64 + 3*128*64];   // 73728 B
    u16* LA = SMEM;                  // [3][64*64]
    u16* LB = SMEM + 3*64*64;        // [3][128*64]
    const int tid = threadIdx.x;
    const int wv = tid >> 6, l = tid & 63;
    const int wc = wv;
    const int lr = l & 31, hl = l >> 5;
    const int m0 = blockIdx.y * 64, f0 = blockIdx.x * 128;

    const u16* Asrc[3] = {Ah, Am, Al};
    const u16* Bsrc[3] = {Wh, Wm, Wl};

    f32x16 acc[2] = {};
    auto frag = [&](const u16* arr, int row, int kb) -> short8v {
        int off = row * 64 + ((kb ^ ((row & 7) << 4)) >> 1);
        return *(const short8v*)&arr[off];
    };

    for (int s = 0; s < KSTEPS; ++s) {
        const int k0 = s * 64;
        __syncthreads();
#pragma unroll
        for (int lvl = 0; lvl < 3; ++lvl) {
#pragma unroll
            for (int p = 0; p < 2; ++p) {
                int g = tid + p * 256;
                int row = g >> 3, ch = (g & 7) * 8;
                *(short8v*)&LA[lvl*4096 + row*64 + ch] =
                    *(const short8v*)&Asrc[lvl][(size_t)(m0 + row) * K + k0 + ch];
            }
#pragma unroll
            for (int p = 0; p < 4; ++p) {
                int g = tid + p * 256;
                int row = g >> 3, ch = (g & 7) * 8;
                *(short8v*)&LB[lvl*8192 + row*64 + ch] =
                    *(const short8v*)&Bsrc[lvl][(size_t)(f0 + row) * K + k0 + ch];
            }
        }
        __syncthreads();
#pragma unroll
        for (int ks = 0; ks < 4; ++ks) {
            const int kb = ks * 32 + hl * 16;
            short8v aF[3][2], bF[3];
#pragma unroll
            for (int lvl = 0; lvl < 3; ++lvl) {
#pragma unroll
                for (int ri = 0; ri < 2; ++ri)
                    aF[lvl][ri] = frag(LA + lvl*4096, ri*32 + lr, kb);
                bF[lvl] = frag(LB + lvl*8192, wc*32 + lr, kb);
            }
            const int pl[6][2] = {{0,2},{2,0},{1,1},{0,1},{1,0},{0,0}};
#pragma unroll
            for (int pp = 0; pp < 6; ++pp)
#pragma unroll
                for (int ri = 0; ri < 2; ++ri)
                    acc[ri] = __builtin_amdgcn_mfma_f32_32x32x16_bf16(
                        aF[pl[pp][0]][ri], bF[pl[pp][1]], acc[ri], 0, 0, 0);
        }
    }

    __syncthreads();
    float* LDSF = (float*)SMEM;
#pragma unroll
    for (int ri = 0; ri < 2; ++ri)
#pragma unroll
        for (int r = 0; r < 16; ++r) {
            int row = ri*32 + (r & 3) + 8*(r >> 2) + 4*hl;
            LDSF[row*132 + wc*32 + lr] = acc[ri][r];
        }
    __syncthreads();
#pragma unroll
    for (int p = 0; p < 4; ++p) {
        int idx = tid + p * 256;
        int row = idx >> 4;
        int g8  = (idx & 15) * 8;
        float v[8], bz[8];
        *(float4*)&v[0]  = *(const float4*)&LDSF[row*132 + g8];
        *(float4*)&v[4]  = *(const float4*)&LDSF[row*132 + g8 + 4];
        *(float4*)&bz[0] = *(const float4*)(bias + f0 + g8);
        *(float4*)&bz[4] = *(const float4*)(bias + f0 + g8 + 4);
        const size_t mrow = m0 + row;
        short8v hh, mm8, ll;
#pragma unroll
        for (int j = 0; j < 8; ++j) {
            float vv = fmaxf(v[j] + bz[j], 0.f);
            v[j] = vv;
            u16 h = f2bf(vv);  float r1 = vv - bf2f(h);
            u16 m = f2bf(r1);  u16 lo = f2bf(r1 - bf2f(m));
            hh[j] = (short)h; mm8[j] = (short)m; ll[j] = (short)lo;
        }
        if constexpr (WRITE_F32) {
            *(float4*)&Hf[mrow * F2_ + f0 + g8]     = *(const float4*)&v[0];
            *(float4*)&Hf[mrow * F2_ + f0 + g8 + 4] = *(const float4*)&v[4];
        }
        const size_t ob = mrow * F2_ + ((size_t)(f0 + g8) ^ ((mrow & 7) << 3));
        *(short8v*)&Hh[ob] = hh;
        *(short8v*)&Hm[ob] = mm8;
        *(short8v*)&Hl[ob] = ll;
    }
}

// ---------------------------------------------------------------------------
// Layer-3 GEMM (fp32 VALU) fused with u / u_hi / u_lo / sq (round-9 proven).
// ---------------------------------------------------------------------------
__global__ __launch_bounds__(256)
void gemm3_fused(const float* __restrict__ A, const float* __restrict__ W,
                 const float* __restrict__ bias, float* __restrict__ C,
                 u16* __restrict__ uh, u16* __restrict__ ul,
                 float* __restrict__ sqv)
{
    constexpr int K = 256;
    __shared__ __align__(16) float As[64][68];
    __shared__ __align__(16) float Ws[64][68];
    const int tid = threadIdx.x;
    const int tx = tid & 15, ty = tid >> 4;
    const int m0 = blockIdx.x * 64;

    float acc[4][4] = {};
    for (int k0 = 0; k0 < K; k0 += 64) {
        __syncthreads();
#pragma unroll
        for (int p = 0; p < 4; ++p) {
            int g = tid + p * 256;
            int r = g >> 4, c = (g & 15) << 2;
            float4 va = *(const float4*)(A + (size_t)(m0 + r) * K + k0 + c);
            As[c+0][r] = va.x; As[c+1][r] = va.y; As[c+2][r] = va.z; As[c+3][r] = va.w;
            float4 vw = *(const float4*)(W + (size_t)r * K + k0 + c);
            Ws[c+0][r] = vw.x; Ws[c+1][r] = vw.y; Ws[c+2][r] = vw.z; Ws[c+3][r] = vw.w;
        }
        __syncthreads();
#pragma unroll
        for (int k = 0; k < 64; ++k) {
            float a[4], w[4];
            *(float4*)&a[0] = *(const float4*)&As[k][ty << 2];
            *(float4*)&w[0] = *(const float4*)&Ws[k][tx << 2];
#pragma unroll
            for (int i = 0; i < 4; ++i)
#pragma unroll
                for (int j = 0; j < 4; ++j)
                    acc[i][j] = fmaf(a[i], w[j], acc[i][j]);
        }
    }

    float4 bz = *(const float4*)(bias + (tx << 2));
    const int slot = tx >> 1;
    const int hoff = (tx & 1) * 4;
#pragma unroll
    for (int i = 0; i < 4; ++i) {
        const int m = m0 + (ty << 2) + i;
        float o[4];
        o[0] = acc[i][0] + bz.x; o[1] = acc[i][1] + bz.y;
        o[2] = acc[i][2] + bz.z; o[3] = acc[i][3] + bz.w;
        *(float4*)(C + (size_t)m * F3_ + (tx << 2)) = *(const float4*)&o[0];
        ushort4 h4, l4;
        h4.x = f2bf(o[0]); l4.x = f2bf(o[0] - bf2f(h4.x));
        h4.y = f2bf(o[1]); l4.y = f2bf(o[1] - bf2f(h4.y));
        h4.z = f2bf(o[2]); l4.z = f2bf(o[2] - bf2f(h4.z));
        h4.w = f2bf(o[3]); l4.w = f2bf(o[3] - bf2f(h4.w));
        const int sb = (((slot * 16) ^ ((m & 7) << 4)) >> 1) + hoff;
        *(ushort4*)&uh[(size_t)m * 64 + sb] = h4;
        *(ushort4*)&ul[(size_t)m * 64 + sb] = l4;
        float s = o[0]*o[0] + o[1]*o[1] + o[2]*o[2] + o[3]*o[3];
#pragma unroll
        for (int msk = 1; msk <= 8; msk <<= 1) s += __shfl_xor(s, msk, 64);
        if (tx == 0) sqv[m] = s;
    }
}

// ---------------------------------------------------------------------------
// Adjacency via split-bf16 MFMA — v5: round-9 structure (coalesced LDS
// staging; r10-r12 showed per-lane global frag loads are uncoalesced & slow)
// but with 64x64 tiles: 4 panels x 8 KB = 32.5 KB LDS -> 4 blocks/CU
// (2x round-9's occupancy, the actual limiter at 47 us / MfmaUtil 9.6%).
// Each of 4 waves owns one 32x32 quadrant (single f32x16 acc, 12 MFMAs).
// Same swizzle/product order/epilogue math -> bit-identical output.
// ---------------------------------------------------------------------------
__global__ __launch_bounds__(256)
void adj_mfma(const u16* __restrict__ uh, const u16* __restrict__ ul,
              const float* __restrict__ uf, const float* __restrict__ sqv,
              unsigned* __restrict__ adj, u64* __restrict__ rmask)
{
    __shared__ u16 UiH[64*64], UiL[64*64];
    __shared__ u16 UjH[64*64], UjL[64*64];
    __shared__ float sqi[64], sqj[64];
    const int tid = threadIdx.x;
    const int jt = blockIdx.x, it = blockIdx.y, b = blockIdx.z;
    const int i0 = it * 64, j0 = jt * 64;
    const size_t ub = (size_t)b * N_;

    if (tid < 64)       sqi[tid] = sqv[ub + i0 + tid];
    else if (tid < 128) sqj[tid - 64] = sqv[ub + j0 + (tid - 64)];

#pragma unroll
    for (int p = 0; p < 2; ++p) {
        int ch = tid + p * 256;   // 0..511 chunks of 8 u16 per panel
        *(short8v*)&UiH[ch * 8] = *(const short8v*)&uh[(ub + i0) * 64 + ch * 8];
        *(short8v*)&UiL[ch * 8] = *(const short8v*)&ul[(ub + i0) * 64 + ch * 8];
        *(short8v*)&UjH[ch * 8] = *(const short8v*)&uh[(ub + j0) * 64 + ch * 8];
        *(short8v*)&UjL[ch * 8] = *(const short8v*)&ul[(ub + j0) * 64 + ch * 8];
    }
    __syncthreads();

    const int w  = tid >> 6, l = tid & 63;
    const int wr = w >> 1,  wc = w & 1;
    const int lr = l & 31,  hl = l >> 5;

    f32x16 acc = {};
    auto frag = [&](const u16* arr, int row, int kb) -> short8v {
        int off = row * 64 + ((kb ^ ((row & 7) << 4)) >> 1);
        return *(const short8v*)&arr[off];
    };
#pragma unroll
    for (int ks = 0; ks < 4; ++ks) {
        const int kb = ks * 32 + hl * 16;
        short8v aH = frag(UiH, wr * 32 + lr, kb);
        short8v aL = frag(UiL, wr * 32 + lr, kb);
        short8v bH = frag(UjH, wc * 32 + lr, kb);
        short8v bL = frag(UjL, wc * 32 + lr, kb);
        acc = __builtin_amdgcn_mfma_f32_32x32x16_bf16(aH, bH, acc, 0, 0, 0);
        acc = __builtin_amdgcn_mfma_f32_32x32x16_bf16(aH, bL, acc, 0, 0, 0);
        acc = __builtin_amdgcn_mfma_f32_32x32x16_bf16(aL, bH, acc, 0, 0, 0);
    }

    {
        const int Rb = wr * 32;
        const int Cb = wc * 32;
        const int jloc = Cb + lr;
        const float sj = sqj[jloc];
#pragma unroll
        for (int r = 0; r < 16; ++r) {
            const int base = (r & 3) + 8 * (r >> 2);
            const int iloc = Rb + base + 4 * hl;
            const float si = sqi[iloc];
            float dv = si + sj - 2.0f * acc[r];
            bool e;
            if (__builtin_expect(fabsf(dv - 1.0f) < 0.02f, 0)) {
                const float* ua = uf + (ub + i0 + iloc) * (size_t)F3_;
                const float* vb = uf + (ub + j0 + jloc) * (size_t)F3_;
                float dot = 0.f;
#pragma unroll 4
                for (int k = 0; k < F3_; ++k) dot = fmaf(ua[k], vb[k], dot);
                e = (si + sj - 2.0f * dot) <= 1.0f;
            } else {
                e = dv <= 1.0f;
            }
            u64 m = __ballot(e);
            if (l == 0) {
                const int I = i0 + Rb + base;
                const int W = (j0 + Cb) >> 5;
                adj[((size_t)b * 64 + W) * N_ + I]     = (unsigned)m;
                adj[((size_t)b * 64 + W) * N_ + I + 4] = (unsigned)(m >> 32);
                if ((unsigned)m)         atomicOr(&rmask[ub + I],     1ull << W);
                if ((unsigned)(m >> 32)) atomicOr(&rmask[ub + I + 4], 1ull << W);
            }
        }
    }
}

// ---------------------------------------------------------------------------
// Connected components: one block per batch, labels in LDS; hook visits only
// the adjacency words flagged in rowmask.
// ---------------------------------------------------------------------------
__global__ __launch_bounds__(1024)
void cc_kernel(const unsigned* __restrict__ adj, const u64* __restrict__ rmask,
               float* __restrict__ out)
{
    __shared__ int Lb[N_];
    __shared__ int chg;
    const int t = threadIdx.x;
    const int b = blockIdx.x;
    const unsigned* ab = adj + (size_t)b * 64 * N_;
    const u64* rm = rmask + (size_t)b * N_;

    Lb[t] = t; Lb[t + 1024] = t + 1024;
    __syncthreads();

    for (int iter = 0; iter < 24; ++iter) {
        if (t == 0) chg = 0;
        __syncthreads();
        int m[2], o[2];
#pragma unroll
        for (int h = 0; h < 2; ++h) {
            int i = t + h * 1024;
            int mm = Lb[i];
            o[h] = mm;
            const unsigned* row = ab + i;
            u64 msk = rm[i];
            while (msk) {
                int w = __ffsll(msk) - 1;
                msk &= msk - 1;
                unsigned v = row[(size_t)w * N_];
                while (v) {
                    int bit = __ffs(v) - 1;
                    v &= v - 1;
                    int lj = Lb[(w << 5) + bit];
                    mm = (lj > mm) ? lj : mm;
                }
            }
            for (int q = 0; q < N_; ++q) {
                int nx = Lb[mm];
                if (nx == mm) break;
                mm = nx;
            }
            m[h] = mm;
        }
        __syncthreads();
        Lb[t] = m[0]; Lb[t + 1024] = m[1];
        if (m[0] != o[0] || m[1] != o[1]) chg = 1;
        __syncthreads();
        if (!chg) break;
    }
    out[(size_t)b * N_ + t]        = (float)Lb[t];
    out[(size_t)b * N_ + t + 1024] = (float)Lb[t + 1024];
}

__global__ __launch_bounds__(256)
void sentinel_kernel(float* out, int n)
{
    int id = blockIdx.x * 256 + threadIdx.x;
    if (id < n) out[id] = -777.0f;
}

// ---------------------------------------------------------------------------
// Triplet loss: one block per batch; thread t handles triplet t (200 < 256).
// ---------------------------------------------------------------------------
__global__ __launch_bounds__(256)
void loss_kernel(const float* __restrict__ u, const float* __restrict__ sq,
                 const int* __restrict__ labels, const int* __restrict__ tri,
                 float* __restrict__ loss)
{
    __shared__ float ssum[256];
    __shared__ int   scnt[256];
    __shared__ int   smax[256];
    const int b = blockIdx.x, t = threadIdx.x;
    const int base = b << 11;

    float mysum = 0.f; int mycnt = 0;
    if (t < 200) {
        int a = tri[3*t+0], p = tri[3*t+1], n = tri[3*t+2];
        int la = labels[base+a], lp = labels[base+p], ln = labels[base+n];
        bool valid = (a != p) && (la == lp) && (lp != ln);
        const float4* ua = (const float4*)(u + (size_t)(base + a) * F3_);
        const float4* up = (const float4*)(u + (size_t)(base + p) * F3_);
        const float4* un = (const float4*)(u + (size_t)(base + n) * F3_);
        float dap = 0.f, dan = 0.f;
#pragma unroll
        for (int q = 0; q < 16; ++q) {
            float4 va = ua[q], vp = up[q], vn = un[q];
            dap += va.x*vp.x + va.y*vp.y + va.z*vp.z + va.w*vp.w;
            dan += va.x*vn.x + va.y*vn.y + va.z*vn.z + va.w*vn.w;
        }
        float d1 = fmaxf(sq[base+a] + sq[base+p] - 2.f*dap, 0.f);
        float d2 = fmaxf(sq[base+a] + sq[base+n] - 2.f*dan, 0.f);
        float tt = fmaxf(d1 - d2 + 2.0f, 0.f);
        if (valid) { mysum = tt; mycnt = 1; }
    }
    int mymax = 0;
    for (int idx = t; idx < N_; idx += 256) {
        int lv = labels[base + idx];
        mymax = (lv > mymax) ? lv : mymax;
    }
    ssum[t] = mysum; scnt[t] = mycnt; smax[t] = mymax;
    __syncthreads();
    for (int s = 128; s > 0; s >>= 1) {
        if (t < s) {
            ssum[t] += ssum[t + s];
            scnt[t] += scnt[t + s];
            smax[t] = (smax[t + s] > smax[t]) ? smax[t + s] : smax[t];
        }
        __syncthreads();
    }
    if (t == 0) {
        int cnt = scnt[0];
        bool use = (smax[0] > 0) && (cnt > 0);
        float contrib = use ? (ssum[0] / (float)(cnt > 1 ? cnt : 1)) : 0.f;
        atomicAdd(loss, contrib);
    }
}

// ---------------------------------------------------------------------------
extern "C" void kernel_launch(void* const* d_in, const int* in_sizes, int n_in,
                              void* d_out, int out_size, void* d_ws, size_t ws_size,
                              hipStream_t stream)
{
    const float* x      = (const float*)d_in[0];
    const int*   labels = (const int*)  d_in[1];
    const int*   tri    = (const int*)  d_in[2];
    const float* W1     = (const float*)d_in[3];
    const float* b1     = (const float*)d_in[4];
    const float* W2     = (const float*)d_in[5];
    const float* b2     = (const float*)d_in[6];
    const float* W3     = (const float*)d_in[7];
    const float* b3     = (const float*)d_in[8];
    float* out = (float*)d_out;

    char* w = (char*)d_ws;
    size_t off = 0;
    auto carve = [&](size_t bytes) -> char* {
        char* p = w + off;
        off += (bytes + 255) & ~(size_t)255;
        return p;
    };
    u16* xh  = (u16*)carve((size_t)NX_  * 2);
    u16* xm  = (u16*)carve((size_t)NX_  * 2);
    u16* xl  = (u16*)carve((size_t)NX_  * 2);
    u16* w1h = (u16*)carve((size_t)NW1_ * 2);
    u16* w1m = (u16*)carve((size_t)NW1_ * 2);
    u16* w1l = (u16*)carve((size_t)NW1_ * 2);
    u16* w2h = (u16*)carve((size_t)NW2_ * 2);
    u16* w2m = (u16*)carve((size_t)NW2_ * 2);
    u16* w2l = (u16*)carve((size_t)NW2_ * 2);
    u16* h1h = (u16*)carve((size_t)M_ * F1_ * 2);
    u16* h1m = (u16*)carve((size_t)M_ * F1_ * 2);
    u16* h1l = (u16*)carve((size_t)M_ * F1_ * 2);
    u16* h2h = (u16*)carve((size_t)M_ * F2_ * 2);
    u16* h2m = (u16*)carve((size_t)M_ * F2_ * 2);
    u16* h2l = (u16*)carve((size_t)M_ * F2_ * 2);
    float* h2f = (float*)carve((size_t)M_ * F2_ * 4);
    float* u   = (float*)carve((size_t)M_ * F3_ * 4);
    u16*   uh  = (u16*)  carve((size_t)M_ * F3_ * 2);
    u16*   ul  = (u16*)  carve((size_t)M_ * F3_ * 2);
    float* sq  = (float*)carve((size_t)M_ * 4);
    unsigned* adj = (unsigned*)carve((size_t)B_ * 64 * N_ * 4);
    u64* rmask = (u64*)carve((size_t)M_ * 8);

    if (off > ws_size) {
        hipLaunchKernelGGL(sentinel_kernel, dim3((out_size + 255) / 256), dim3(256),
                           0, stream, out, out_size);
        return;
    }

    constexpr int NTOT = NX_ + NW1_ + NW2_;
    hipLaunchKernelGGL(split3_kernel, dim3((NTOT + 255) / 256), dim3(256), 0, stream,
                       x, W1, W2, xh, xm, xl, w1h, w1m, w1l, w2h, w2m, w2l,
                       rmask, out + M_);

    hipLaunchKernelGGL((gemm_mfma<2, 0>), dim3(F1_/128, M_/64), dim3(256), 0, stream,
                       xh, xm, xl, w1h, w1m, w1l, b1, h1h, h1m, h1l, (float*)nullptr);
    hipLaunchKernelGGL((gemm_mfma<4, 1>), dim3(F2_/128, M_/64), dim3(256), 0, stream,
                       h1h, h1m, h1l, w2h, w2m, w2l, b2, h2h, h2m, h2l, h2f);

    hipLaunchKernelGGL(gemm3_fused, dim3(M_/64), dim3(256), 0, stream,
                       h2f, W3, b3, u, uh, ul, sq);

    hipLaunchKernelGGL(adj_mfma, dim3(N_/64, N_/64, B_), dim3(256), 0, stream,
                       uh, ul, u, sq, adj, rmask);

    hipLaunchKernelGGL(loss_kernel, dim3(B_), dim3(256), 0, stream,
                       u, sq, labels, tri, out + M_);

    hipLaunchKernelGGL(cc_kernel, dim3(B_), dim3(1024), 0, stream,
                       adj, rmask, out);
}